// Round 4
// baseline (569.553 us; speedup 1.0000x reference)
//
#include <hip/hip_runtime.h>

#define NB 8
#define NN 1024
#define NH 8
#define HD 96
#define DIM 768

typedef __bf16 bf16x8 __attribute__((ext_vector_type(8)));
typedef float f32x4 __attribute__((ext_vector_type(4)));
typedef unsigned short u16x8 __attribute__((ext_vector_type(8)));

__device__ __forceinline__ ushort f2bf(float f) {
  uint u = __float_as_uint(f);
  u += 0x7fffu + ((u >> 16) & 1u);
  return (ushort)(u >> 16);
}
__device__ __forceinline__ float bf2f(ushort u) {
  return __uint_as_float(((uint)u) << 16);
}

// ---------------- K0b: proj_w [768][768] f32 -> wT bf16 [j][d] ----------------
__global__ __launch_bounds__(256) void k_prep_w(const float* __restrict__ pw,
                                                ushort* __restrict__ wT) {
  __shared__ ushort tile[64][72];
  int d0 = blockIdx.x * 64;
  int j0 = blockIdx.y * 64;
  int t = threadIdx.x;
  {
    int r = t >> 2;
    int ch = (t & 3) * 16;
    const float* src = pw + (size_t)(d0 + r) * DIM + j0 + ch;
#pragma unroll
    for (int i = 0; i < 16; i += 4) {
      float4 v = *(const float4*)(src + i);
      tile[ch + i + 0][r] = f2bf(v.x);
      tile[ch + i + 1][r] = f2bf(v.y);
      tile[ch + i + 2][r] = f2bf(v.z);
      tile[ch + i + 3][r] = f2bf(v.w);
    }
  }
  __syncthreads();
  {
    int j = t >> 2;
    int ch = (t & 3) * 16;
    union { ushort u[16]; uint4 v[2]; } tmp;
#pragma unroll
    for (int i = 0; i < 16; ++i) tmp.u[i] = tile[j][ch + i];
    uint4* dst = (uint4*)(wT + (size_t)(j0 + j) * DIM + d0 + ch);
    dst[0] = tmp.v[0]; dst[1] = tmp.v[1];
  }
}

// ---------------- K1: 3x3 SAME conv per 16x16x3 token image -> q bf16 ----------------
__global__ __launch_bounds__(256) void k_conv(const float* __restrict__ x,
                                              const float* __restrict__ w,
                                              ushort* __restrict__ q) {
  __shared__ float xs[768];
  __shared__ float ws[81];
  __shared__ ushort os[768];
  int token = blockIdx.x;
  int t = threadIdx.x;
  const float4* xin = (const float4*)(x + (size_t)token * DIM);
  if (t < 192) ((float4*)xs)[t] = xin[t];
  if (t < 81) ws[t] = w[t];
  __syncthreads();
  int r = t >> 4, c = t & 15;
  float a0 = 0.f, a1 = 0.f, a2 = 0.f;
#pragma unroll
  for (int dr = 0; dr < 3; ++dr) {
    int rr = r + dr - 1;
    bool rok = (rr >= 0) & (rr < 16);
#pragma unroll
    for (int dc = 0; dc < 3; ++dc) {
      int cc = c + dc - 1;
      bool ok = rok & (cc >= 0) & (cc < 16);
#pragma unroll
      for (int ci = 0; ci < 3; ++ci) {
        int idx = ok ? (rr * 16 + cc) * 3 + ci : 0;
        float xv = xs[idx];
        xv = ok ? xv : 0.f;
        const float* wp = ws + ((dr * 3 + dc) * 3 + ci) * 3;
        a0 += xv * wp[0]; a1 += xv * wp[1]; a2 += xv * wp[2];
      }
    }
  }
  os[t * 3 + 0] = f2bf(a0);
  os[t * 3 + 1] = f2bf(a1);
  os[t * 3 + 2] = f2bf(a2);
  __syncthreads();
  uint4* dst = (uint4*)(q + (size_t)token * DIM);
  if (t < 96) dst[t] = ((const uint4*)os)[t];
}

// ---------------- K1b: q [b][n][d] -> qT [b][d][n] (bf16) ----------------
__global__ __launch_bounds__(256) void k_transpose_q(const ushort* __restrict__ q,
                                                     ushort* __restrict__ qT) {
  __shared__ ushort tile[64][72];
  int bb = blockIdx.z;
  int n0 = blockIdx.x * 64;
  int d0 = blockIdx.y * 64;
  int t = threadIdx.x;
  {
    int r = t >> 2;
    int cq = (t & 3) * 16;
    const ushort* src = q + ((size_t)(bb * NN) + n0 + r) * DIM + d0 + cq;
    uint4 v0 = *(const uint4*)src;
    uint4 v1 = *(const uint4*)(src + 8);
    *(uint4*)&tile[r][cq] = v0;
    *(uint4*)&tile[r][cq + 8] = v1;
  }
  __syncthreads();
  {
    int d = t >> 2;
    int nch = (t & 3) * 16;
    union { ushort u[16]; uint4 v[2]; } tmp;
#pragma unroll
    for (int j = 0; j < 16; ++j) tmp.u[j] = tile[nch + j][d];
    uint4* dst = (uint4*)(qT + ((size_t)(bb * DIM) + d0 + d) * NN + n0 + nch);
    dst[0] = tmp.v[0]; dst[1] = tmp.v[1];
  }
}

// ---------------- K1c: colsum[b][d] = sum_n q[b][n][d] ----------------
__global__ __launch_bounds__(128) void k_colsum(const ushort* __restrict__ q,
                                                float* __restrict__ cs) {
  int bb = blockIdx.y;
  int c = blockIdx.x * 128 + threadIdx.x;
  const ushort* p = q + (size_t)bb * NN * DIM + c;
  float s = 0.f;
#pragma unroll 16
  for (int n = 0; n < NN; ++n) s += bf2f(p[(size_t)n * DIM]);
  cs[bb * DIM + c] = s;
}

// ---------------- K2: fused QK^T + softmax + head-mix/BN + attn write + PV ----------------
// 512 threads = 8 waves. Wave w: head h=w for QK^T/softmax, channel g=w for mix/PV.
// Block: (b, 16-row n-tile). 512 blocks -> 2 blocks/CU. lin&7 -> batch (XCD L2 locality).
// P double-buffered: ONE barrier per mt-iter; attn-store drain overlaps phase3+next phase1.
__global__ __launch_bounds__(512, 4) void k_attn_fused(
    const ushort* __restrict__ q, const ushort* __restrict__ qT,
    const float* __restrict__ cs,
    const float* __restrict__ rw, const float* __restrict__ rb,
    const float* __restrict__ gamma, const float* __restrict__ beta,
    const float* __restrict__ mean, const float* __restrict__ var,
    float* __restrict__ attn, ushort* __restrict__ outb) {
  __shared__ ushort P[2][8192];  // [2][8 heads][16 n][64 m] bf16, XOR-swizzled, 32 KB

  const int lin = blockIdx.x;
  const int bb = lin & 7;
  const int nt = lin >> 3;
  const int n0 = nt * 16;
  const int t = threadIdx.x;
  const int w = t >> 6, lane = t & 63;
  const int lm = lane & 15, lg = lane >> 4;
  const float scale = 0.10206207261596575f;  // 96^-0.5

  float wreg[8];
#pragma unroll
  for (int h = 0; h < 8; ++h) wreg[h] = rw[h * 8 + w];
  const float effs = gamma[w] * __frsqrt_rn(var[w] + 1e-3f);
  const float effb = (rb[w] - mean[w]) * effs + beta[w];

  const ushort* qb = q + (size_t)bb * NN * DIM;
  const ushort* vb = qT + (size_t)bb * DIM * NN;

  // Q fragments for head w: [ks]
  bf16x8 qf[3];
#pragma unroll
  for (int ks = 0; ks < 3; ++ks)
    qf[ks] = *(const bf16x8*)(qb + (size_t)(n0 + lm) * DIM + w * HD + ks * 32 + lg * 8);

  // ---------------- pass A: rowsums of exp(S*scale) ----------------
  float rs[4] = {0.f, 0.f, 0.f, 0.f};
  for (int mt = 0; mt < 16; ++mt) {
    const int m0 = mt * 64;
    bf16x8 kf[3][4];
#pragma unroll
    for (int ks = 0; ks < 3; ++ks)
#pragma unroll
      for (int mf = 0; mf < 4; ++mf)
        kf[ks][mf] = *(const bf16x8*)(qb + (size_t)(m0 + mf * 16 + lm) * DIM
                                       + w * HD + ks * 32 + lg * 8);
    f32x4 sacc[4] = {};
#pragma unroll
    for (int ks = 0; ks < 3; ++ks)
#pragma unroll
      for (int mf = 0; mf < 4; ++mf)
        sacc[mf] = __builtin_amdgcn_mfma_f32_16x16x32_bf16(qf[ks], kf[ks][mf], sacc[mf], 0, 0, 0);
#pragma unroll
    for (int mf = 0; mf < 4; ++mf)
#pragma unroll
      for (int r = 0; r < 4; ++r)
        rs[r] += __expf(sacc[mf][r] * scale);
  }
  float inv[4];
#pragma unroll
  for (int r = 0; r < 4; ++r) {
    float s = rs[r];
    s += __shfl_xor(s, 1); s += __shfl_xor(s, 2);
    s += __shfl_xor(s, 4); s += __shfl_xor(s, 8);
    inv[r] = 1.f / s;
  }

  // ---------------- pass B ----------------
  f32x4 oacc[6] = {};  // [df] PV accumulator

  for (int mt = 0; mt < 16; ++mt) {
    const int m0 = mt * 64;
    char* Pc = (char*)P + (mt & 1) * 16384;
    // phase 1: recompute S (identical MFMA order), normalize, p -> LDS[cur]
    {
      bf16x8 kf[3][4];
#pragma unroll
      for (int ks = 0; ks < 3; ++ks)
#pragma unroll
        for (int mf = 0; mf < 4; ++mf)
          kf[ks][mf] = *(const bf16x8*)(qb + (size_t)(m0 + mf * 16 + lm) * DIM
                                         + w * HD + ks * 32 + lg * 8);
      f32x4 sacc[4] = {};
#pragma unroll
      for (int ks = 0; ks < 3; ++ks)
#pragma unroll
        for (int mf = 0; mf < 4; ++mf)
          sacc[mf] = __builtin_amdgcn_mfma_f32_16x16x32_bf16(qf[ks], kf[ks][mf], sacc[mf], 0, 0, 0);
#pragma unroll
      for (int mf = 0; mf < 4; ++mf)
#pragma unroll
        for (int r = 0; r < 4; ++r) {
          float e = __expf(sacc[mf][r] * scale) * inv[r];
          int n = lg * 4 + r;
          int mbyte = 2 * (mf * 16 + lm);
          int addr = w * 2048 + n * 128 + (mbyte ^ ((n & 7) << 4));
          *(ushort*)(Pc + addr) = f2bf(e);
        }
    }
    __syncthreads();
    // phase 2: V frag loads (overlap with LDS mix), mix heads -> g=w, BN store, pack frags
    bf16x8 vf[2][6];
#pragma unroll
    for (int ks = 0; ks < 2; ++ks)
#pragma unroll
      for (int df = 0; df < 6; ++df)
        vf[ks][df] = *(const bf16x8*)(vb + (size_t)(w * HD + df * 16 + lm) * NN
                                       + m0 + ks * 32 + lg * 8);
    bf16x8 pmf[2];
    {
      int n = lm;
      int swz = (n & 7) << 4;
#pragma unroll
      for (int ks = 0; ks < 2; ++ks) {
        int rbase = n * 128 + ((2 * (ks * 32 + lg * 8)) ^ swz);
        float mix[8];
#pragma unroll
        for (int j = 0; j < 8; ++j) mix[j] = 0.f;
#pragma unroll
        for (int h = 0; h < 8; ++h) {
          u16x8 pu = *(const u16x8*)(Pc + h * 2048 + rbase);
#pragma unroll
          for (int j = 0; j < 8; ++j) mix[j] += bf2f(pu[j]) * wreg[h];
        }
        f32x4 o0, o1;
        o0[0] = mix[0] * effs + effb; o0[1] = mix[1] * effs + effb;
        o0[2] = mix[2] * effs + effb; o0[3] = mix[3] * effs + effb;
        o1[0] = mix[4] * effs + effb; o1[1] = mix[5] * effs + effb;
        o1[2] = mix[6] * effs + effb; o1[3] = mix[7] * effs + effb;
        size_t arow = ((size_t)(bb * 8 + w) * NN + (n0 + n)) * NN + m0 + ks * 32 + lg * 8;
        __builtin_nontemporal_store(o0, (f32x4*)(attn + arow));
        __builtin_nontemporal_store(o1, (f32x4*)(attn + arow + 4));
        u16x8 pk;
#pragma unroll
        for (int j = 0; j < 8; ++j) pk[j] = f2bf(mix[j]);
        pmf[ks] = *(bf16x8*)&pk;
      }
    }
    // phase 3: PV MFMA (no second barrier: next iter writes the other P buffer)
#pragma unroll
    for (int ks = 0; ks < 2; ++ks)
#pragma unroll
      for (int df = 0; df < 6; ++df)
        oacc[df] = __builtin_amdgcn_mfma_f32_16x16x32_bf16(pmf[ks], vf[ks][df], oacc[df], 0, 0, 0);
  }

  // epilogue: outb = bf16(effs*acc + effb*colsum)
#pragma unroll
  for (int df = 0; df < 6; ++df) {
    int col = w * HD + df * 16 + lm;
    float csv = cs[bb * DIM + col] * effb;
#pragma unroll
    for (int r = 0; r < 4; ++r) {
      int row = n0 + lg * 4 + r;
      outb[(size_t)(bb * NN + row) * DIM + col] = f2bf(oacc[df][r] * effs + csv);
    }
  }
}

// ---------------- K6: xo = out @ proj_w + proj_b (bf16 MFMA, fp32 out) ----------------
__global__ __launch_bounds__(256) void k_proj(const ushort* __restrict__ outb,
                                              const ushort* __restrict__ wT,
                                              const float* __restrict__ pb,
                                              float* __restrict__ xo) {
  __shared__ ushort As[128][72];
  __shared__ ushort Bs[128][72];
  int m0 = blockIdx.x * 128;
  int j0 = blockIdx.y * 128;
  int t = threadIdx.x;
  int wv = t >> 6, lane = t & 63;
  int wr = (wv >> 1) * 64, wc = (wv & 1) * 64;
  int lm = lane & 15, lg = lane >> 4;
  f32x4 acc[4][4] = {};
  for (int kk = 0; kk < 12; ++kk) {
    int k0 = kk * 64;
    __syncthreads();
    for (int i = t; i < 1024; i += 256) {
      int row = i >> 3;
      int c = (i & 7) * 8;
      *(uint4*)&As[row][c] = *(const uint4*)(outb + (size_t)(m0 + row) * DIM + k0 + c);
      *(uint4*)&Bs[row][c] = *(const uint4*)(wT + (size_t)(j0 + row) * DIM + k0 + c);
    }
    __syncthreads();
#pragma unroll
    for (int ks = 0; ks < 2; ++ks) {
      bf16x8 af[4], bfr[4];
#pragma unroll
      for (int mi = 0; mi < 4; ++mi)
        af[mi] = *(const bf16x8*)&As[wr + mi * 16 + lm][ks * 32 + lg * 8];
#pragma unroll
      for (int ni = 0; ni < 4; ++ni)
        bfr[ni] = *(const bf16x8*)&Bs[wc + ni * 16 + lm][ks * 32 + lg * 8];
#pragma unroll
      for (int mi = 0; mi < 4; ++mi)
#pragma unroll
        for (int ni = 0; ni < 4; ++ni)
          acc[mi][ni] = __builtin_amdgcn_mfma_f32_16x16x32_bf16(af[mi], bfr[ni], acc[mi][ni], 0, 0, 0);
    }
  }
#pragma unroll
  for (int ni = 0; ni < 4; ++ni) {
    int col = j0 + wc + ni * 16 + lm;
    float bias = pb[col];
#pragma unroll
    for (int mi = 0; mi < 4; ++mi)
#pragma unroll
      for (int r = 0; r < 4; ++r) {
        int row = m0 + wr + mi * 16 + lg * 4 + r;
        xo[(size_t)row * DIM + col] = acc[mi][ni][r] + bias;
      }
  }
}

extern "C" void kernel_launch(void* const* d_in, const int* in_sizes, int n_in,
                              void* d_out, int out_size, void* d_ws, size_t ws_size,
                              hipStream_t stream) {
  (void)in_sizes; (void)n_in; (void)out_size; (void)ws_size;
  const float* x       = (const float*)d_in[0];
  const float* qconv_w = (const float*)d_in[1];
  const float* rw      = (const float*)d_in[2];
  const float* rb      = (const float*)d_in[3];
  const float* gamma   = (const float*)d_in[4];
  const float* beta    = (const float*)d_in[5];
  const float* mean    = (const float*)d_in[6];
  const float* var     = (const float*)d_in[7];
  const float* pw      = (const float*)d_in[8];
  const float* pb      = (const float*)d_in[9];

  float* xo   = (float*)d_out;
  float* attn = xo + (size_t)NB * NN * DIM;  // attn_next output region

  char* ws = (char*)d_ws;
  ushort* q    = (ushort*)(ws);                 // [8][1024][768] bf16: 12,582,912 B
  ushort* qT   = (ushort*)(ws + 12582912);      // [8][768][1024] bf16: 12,582,912 B
  ushort* wT   = (ushort*)(ws + 25165824);      // [768][768] bf16:      1,179,648 B
  ushort* outb = (ushort*)(ws + 26345472);      // [8192][768] bf16:    12,582,912 B
  float*  csum = (float*)(ws + 38928384);       // [8][768] f32:            24,576 B

  hipLaunchKernelGGL(k_prep_w, dim3(12, 12), dim3(256), 0, stream, pw, wT);
  hipLaunchKernelGGL(k_conv, dim3(NB * NN), dim3(256), 0, stream, x, qconv_w, q);
  hipLaunchKernelGGL(k_transpose_q, dim3(16, 12, NB), dim3(256), 0, stream, q, qT);
  hipLaunchKernelGGL(k_colsum, dim3(6, NB), dim3(128), 0, stream, q, csum);
  hipLaunchKernelGGL(k_attn_fused, dim3(512), dim3(512), 0, stream, q, qT, csum,
                     rw, rb, gamma, beta, mean, var, attn, outb);
  hipLaunchKernelGGL(k_proj, dim3(64, 6), dim3(256), 0, stream, outb, wT, pb, xo);
}

// Round 5
// 401.537 us; speedup vs baseline: 1.4184x; 1.4184x over previous
//
#include <hip/hip_runtime.h>

#define NB 8
#define NN 1024
#define NH 8
#define HD 96
#define DIM 768

typedef __bf16 bf16x8 __attribute__((ext_vector_type(8)));
typedef float f32x4 __attribute__((ext_vector_type(4)));
typedef unsigned short u16x8 __attribute__((ext_vector_type(8)));

__device__ __forceinline__ ushort f2bf(float f) {
  uint u = __float_as_uint(f);
  u += 0x7fffu + ((u >> 16) & 1u);
  return (ushort)(u >> 16);
}
__device__ __forceinline__ float bf2f(ushort u) {
  return __uint_as_float(((uint)u) << 16);
}

// ---------------- K0b: proj_w [768][768] f32 -> wT bf16 [j][d] ----------------
__global__ __launch_bounds__(256) void k_prep_w(const float* __restrict__ pw,
                                                ushort* __restrict__ wT) {
  __shared__ ushort tile[64][72];
  int d0 = blockIdx.x * 64;
  int j0 = blockIdx.y * 64;
  int t = threadIdx.x;
  {
    int r = t >> 2;
    int ch = (t & 3) * 16;
    const float* src = pw + (size_t)(d0 + r) * DIM + j0 + ch;
#pragma unroll
    for (int i = 0; i < 16; i += 4) {
      float4 v = *(const float4*)(src + i);
      tile[ch + i + 0][r] = f2bf(v.x);
      tile[ch + i + 1][r] = f2bf(v.y);
      tile[ch + i + 2][r] = f2bf(v.z);
      tile[ch + i + 3][r] = f2bf(v.w);
    }
  }
  __syncthreads();
  {
    int j = t >> 2;
    int ch = (t & 3) * 16;
    union { ushort u[16]; uint4 v[2]; } tmp;
#pragma unroll
    for (int i = 0; i < 16; ++i) tmp.u[i] = tile[j][ch + i];
    uint4* dst = (uint4*)(wT + (size_t)(j0 + j) * DIM + d0 + ch);
    dst[0] = tmp.v[0]; dst[1] = tmp.v[1];
  }
}

// ---------------- K1: 3x3 SAME conv per 16x16x3 token image -> q bf16 ----------------
__global__ __launch_bounds__(256) void k_conv(const float* __restrict__ x,
                                              const float* __restrict__ w,
                                              ushort* __restrict__ q) {
  __shared__ float xs[768];
  __shared__ float ws[81];
  __shared__ ushort os[768];
  int token = blockIdx.x;
  int t = threadIdx.x;
  const float4* xin = (const float4*)(x + (size_t)token * DIM);
  if (t < 192) ((float4*)xs)[t] = xin[t];
  if (t < 81) ws[t] = w[t];
  __syncthreads();
  int r = t >> 4, c = t & 15;
  float a0 = 0.f, a1 = 0.f, a2 = 0.f;
#pragma unroll
  for (int dr = 0; dr < 3; ++dr) {
    int rr = r + dr - 1;
    bool rok = (rr >= 0) & (rr < 16);
#pragma unroll
    for (int dc = 0; dc < 3; ++dc) {
      int cc = c + dc - 1;
      bool ok = rok & (cc >= 0) & (cc < 16);
#pragma unroll
      for (int ci = 0; ci < 3; ++ci) {
        int idx = ok ? (rr * 16 + cc) * 3 + ci : 0;
        float xv = xs[idx];
        xv = ok ? xv : 0.f;
        const float* wp = ws + ((dr * 3 + dc) * 3 + ci) * 3;
        a0 += xv * wp[0]; a1 += xv * wp[1]; a2 += xv * wp[2];
      }
    }
  }
  os[t * 3 + 0] = f2bf(a0);
  os[t * 3 + 1] = f2bf(a1);
  os[t * 3 + 2] = f2bf(a2);
  __syncthreads();
  uint4* dst = (uint4*)(q + (size_t)token * DIM);
  if (t < 96) dst[t] = ((const uint4*)os)[t];
}

// ---------------- K1b: q [b][n][d] -> qT [b][d][n] (bf16) ----------------
__global__ __launch_bounds__(256) void k_transpose_q(const ushort* __restrict__ q,
                                                     ushort* __restrict__ qT) {
  __shared__ ushort tile[64][72];
  int bb = blockIdx.z;
  int n0 = blockIdx.x * 64;
  int d0 = blockIdx.y * 64;
  int t = threadIdx.x;
  {
    int r = t >> 2;
    int cq = (t & 3) * 16;
    const ushort* src = q + ((size_t)(bb * NN) + n0 + r) * DIM + d0 + cq;
    uint4 v0 = *(const uint4*)src;
    uint4 v1 = *(const uint4*)(src + 8);
    *(uint4*)&tile[r][cq] = v0;
    *(uint4*)&tile[r][cq + 8] = v1;
  }
  __syncthreads();
  {
    int d = t >> 2;
    int nch = (t & 3) * 16;
    union { ushort u[16]; uint4 v[2]; } tmp;
#pragma unroll
    for (int j = 0; j < 16; ++j) tmp.u[j] = tile[nch + j][d];
    uint4* dst = (uint4*)(qT + ((size_t)(bb * DIM) + d0 + d) * NN + n0 + nch);
    dst[0] = tmp.v[0]; dst[1] = tmp.v[1];
  }
}

// ---------------- K1c: colsum[b][d] = sum_n q[b][n][d] ----------------
__global__ __launch_bounds__(128) void k_colsum(const ushort* __restrict__ q,
                                                float* __restrict__ cs) {
  int bb = blockIdx.y;
  int c = blockIdx.x * 128 + threadIdx.x;
  const ushort* p = q + (size_t)bb * NN * DIM + c;
  float s = 0.f;
#pragma unroll 16
  for (int n = 0; n < NN; ++n) s += bf2f(p[(size_t)n * DIM]);
  cs[bb * DIM + c] = s;
}

// ---------------- K2: fused QK^T + softmax + head-mix/BN + attn write + PV ----------------
// 512 threads = 8 waves. Wave w: head h=w for QK^T/softmax, channel g=w for mix/PV.
// Block: (b, 16-row n-tile). 512 blocks -> 2 blocks/CU (needs VGPR<=128: kf split per-mf,
// vf split per-ks keep peak demand ~110). lin&7 -> batch (XCD L2 locality).
// P double-buffered: ONE barrier per mt-iter.
__global__ __launch_bounds__(512, 2) void k_attn_fused(
    const ushort* __restrict__ q, const ushort* __restrict__ qT,
    const float* __restrict__ cs,
    const float* __restrict__ rw, const float* __restrict__ rb,
    const float* __restrict__ gamma, const float* __restrict__ beta,
    const float* __restrict__ mean, const float* __restrict__ var,
    float* __restrict__ attn, ushort* __restrict__ outb) {
  __shared__ ushort P[2][8192];  // [2][8 heads][16 n][64 m] bf16, XOR-swizzled, 32 KB

  const int lin = blockIdx.x;
  const int bb = lin & 7;
  const int nt = lin >> 3;
  const int n0 = nt * 16;
  const int t = threadIdx.x;
  const int w = t >> 6, lane = t & 63;
  const int lm = lane & 15, lg = lane >> 4;
  const float scale = 0.10206207261596575f;  // 96^-0.5

  float wreg[8];
#pragma unroll
  for (int h = 0; h < 8; ++h) wreg[h] = rw[h * 8 + w];
  const float effs = gamma[w] * __frsqrt_rn(var[w] + 1e-3f);
  const float effb = (rb[w] - mean[w]) * effs + beta[w];

  const ushort* qb = q + (size_t)bb * NN * DIM;
  const ushort* vb = qT + (size_t)bb * DIM * NN;
  const ushort* kb = qb + w * HD + (size_t)lm * DIM + lg * 8;  // per-lane K base

  // Q fragments for head w: [ks]
  bf16x8 qf[3];
#pragma unroll
  for (int ks = 0; ks < 3; ++ks)
    qf[ks] = *(const bf16x8*)(qb + (size_t)(n0 + lm) * DIM + w * HD + ks * 32 + lg * 8);

  // ---------------- pass A: rowsums of exp(S*scale) ----------------
  float rs[4] = {0.f, 0.f, 0.f, 0.f};
  for (int mt = 0; mt < 16; ++mt) {
    const int m0 = mt * 64;
    f32x4 sacc[4] = {};
#pragma unroll
    for (int mf = 0; mf < 4; ++mf) {
      const ushort* kp = kb + (size_t)(m0 + mf * 16) * DIM;
      bf16x8 k0 = *(const bf16x8*)(kp);
      bf16x8 k1 = *(const bf16x8*)(kp + 32);
      bf16x8 k2 = *(const bf16x8*)(kp + 64);
      sacc[mf] = __builtin_amdgcn_mfma_f32_16x16x32_bf16(qf[0], k0, sacc[mf], 0, 0, 0);
      sacc[mf] = __builtin_amdgcn_mfma_f32_16x16x32_bf16(qf[1], k1, sacc[mf], 0, 0, 0);
      sacc[mf] = __builtin_amdgcn_mfma_f32_16x16x32_bf16(qf[2], k2, sacc[mf], 0, 0, 0);
    }
#pragma unroll
    for (int mf = 0; mf < 4; ++mf)
#pragma unroll
      for (int r = 0; r < 4; ++r)
        rs[r] += __expf(sacc[mf][r] * scale);
  }
  float inv[4];
#pragma unroll
  for (int r = 0; r < 4; ++r) {
    float s = rs[r];
    s += __shfl_xor(s, 1); s += __shfl_xor(s, 2);
    s += __shfl_xor(s, 4); s += __shfl_xor(s, 8);
    inv[r] = 1.f / s;
  }

  // ---------------- pass B ----------------
  f32x4 oacc[6] = {};  // [df] PV accumulator

  for (int mt = 0; mt < 16; ++mt) {
    const int m0 = mt * 64;
    char* Pc = (char*)P + (mt & 1) * 16384;
    // phase 1: recompute S (identical per-sacc accumulation order), normalize, p -> LDS
    {
      f32x4 sacc[4] = {};
#pragma unroll
      for (int mf = 0; mf < 4; ++mf) {
        const ushort* kp = kb + (size_t)(m0 + mf * 16) * DIM;
        bf16x8 k0 = *(const bf16x8*)(kp);
        bf16x8 k1 = *(const bf16x8*)(kp + 32);
        bf16x8 k2 = *(const bf16x8*)(kp + 64);
        sacc[mf] = __builtin_amdgcn_mfma_f32_16x16x32_bf16(qf[0], k0, sacc[mf], 0, 0, 0);
        sacc[mf] = __builtin_amdgcn_mfma_f32_16x16x32_bf16(qf[1], k1, sacc[mf], 0, 0, 0);
        sacc[mf] = __builtin_amdgcn_mfma_f32_16x16x32_bf16(qf[2], k2, sacc[mf], 0, 0, 0);
      }
#pragma unroll
      for (int mf = 0; mf < 4; ++mf)
#pragma unroll
        for (int r = 0; r < 4; ++r) {
          float e = __expf(sacc[mf][r] * scale) * inv[r];
          int n = lg * 4 + r;
          int mbyte = 2 * (mf * 16 + lm);
          int addr = w * 2048 + n * 128 + (mbyte ^ ((n & 7) << 4));
          *(ushort*)(Pc + addr) = f2bf(e);
        }
    }
    __syncthreads();
    // phase 2: mix heads -> g=w from LDS, BN store to attn, pack pm frags
    bf16x8 pmf[2];
    {
      int n = lm;
      int swz = (n & 7) << 4;
#pragma unroll
      for (int ks = 0; ks < 2; ++ks) {
        int rbase = n * 128 + ((2 * (ks * 32 + lg * 8)) ^ swz);
        float mix[8];
#pragma unroll
        for (int j = 0; j < 8; ++j) mix[j] = 0.f;
#pragma unroll
        for (int h = 0; h < 8; ++h) {
          u16x8 pu = *(const u16x8*)(Pc + h * 2048 + rbase);
#pragma unroll
          for (int j = 0; j < 8; ++j) mix[j] += bf2f(pu[j]) * wreg[h];
        }
        f32x4 o0, o1;
        o0[0] = mix[0] * effs + effb; o0[1] = mix[1] * effs + effb;
        o0[2] = mix[2] * effs + effb; o0[3] = mix[3] * effs + effb;
        o1[0] = mix[4] * effs + effb; o1[1] = mix[5] * effs + effb;
        o1[2] = mix[6] * effs + effb; o1[3] = mix[7] * effs + effb;
        size_t arow = ((size_t)(bb * 8 + w) * NN + (n0 + n)) * NN + m0 + ks * 32 + lg * 8;
        __builtin_nontemporal_store(o0, (f32x4*)(attn + arow));
        __builtin_nontemporal_store(o1, (f32x4*)(attn + arow + 4));
        u16x8 pk;
#pragma unroll
        for (int j = 0; j < 8; ++j) pk[j] = f2bf(mix[j]);
        pmf[ks] = *(bf16x8*)&pk;
      }
    }
    // phase 3: PV MFMA, vf split per-ks (24 live VGPRs instead of 48)
#pragma unroll
    for (int ks = 0; ks < 2; ++ks) {
      bf16x8 vf[6];
#pragma unroll
      for (int df = 0; df < 6; ++df)
        vf[df] = *(const bf16x8*)(vb + (size_t)(w * HD + df * 16 + lm) * NN
                                   + m0 + ks * 32 + lg * 8);
#pragma unroll
      for (int df = 0; df < 6; ++df)
        oacc[df] = __builtin_amdgcn_mfma_f32_16x16x32_bf16(pmf[ks], vf[df], oacc[df], 0, 0, 0);
    }
  }

  // epilogue: outb = bf16(effs*acc + effb*colsum)
#pragma unroll
  for (int df = 0; df < 6; ++df) {
    int col = w * HD + df * 16 + lm;
    float csv = cs[bb * DIM + col] * effb;
#pragma unroll
    for (int r = 0; r < 4; ++r) {
      int row = n0 + lg * 4 + r;
      outb[(size_t)(bb * NN + row) * DIM + col] = f2bf(oacc[df][r] * effs + csv);
    }
  }
}

// ---------------- K6: xo = out @ proj_w + proj_b (bf16 MFMA, fp32 out) ----------------
__global__ __launch_bounds__(256) void k_proj(const ushort* __restrict__ outb,
                                              const ushort* __restrict__ wT,
                                              const float* __restrict__ pb,
                                              float* __restrict__ xo) {
  __shared__ ushort As[128][72];
  __shared__ ushort Bs[128][72];
  int m0 = blockIdx.x * 128;
  int j0 = blockIdx.y * 128;
  int t = threadIdx.x;
  int wv = t >> 6, lane = t & 63;
  int wr = (wv >> 1) * 64, wc = (wv & 1) * 64;
  int lm = lane & 15, lg = lane >> 4;
  f32x4 acc[4][4] = {};
  for (int kk = 0; kk < 12; ++kk) {
    int k0 = kk * 64;
    __syncthreads();
    for (int i = t; i < 1024; i += 256) {
      int row = i >> 3;
      int c = (i & 7) * 8;
      *(uint4*)&As[row][c] = *(const uint4*)(outb + (size_t)(m0 + row) * DIM + k0 + c);
      *(uint4*)&Bs[row][c] = *(const uint4*)(wT + (size_t)(j0 + row) * DIM + k0 + c);
    }
    __syncthreads();
#pragma unroll
    for (int ks = 0; ks < 2; ++ks) {
      bf16x8 af[4], bfr[4];
#pragma unroll
      for (int mi = 0; mi < 4; ++mi)
        af[mi] = *(const bf16x8*)&As[wr + mi * 16 + lm][ks * 32 + lg * 8];
#pragma unroll
      for (int ni = 0; ni < 4; ++ni)
        bfr[ni] = *(const bf16x8*)&Bs[wc + ni * 16 + lm][ks * 32 + lg * 8];
#pragma unroll
      for (int mi = 0; mi < 4; ++mi)
#pragma unroll
        for (int ni = 0; ni < 4; ++ni)
          acc[mi][ni] = __builtin_amdgcn_mfma_f32_16x16x32_bf16(af[mi], bfr[ni], acc[mi][ni], 0, 0, 0);
    }
  }
#pragma unroll
  for (int ni = 0; ni < 4; ++ni) {
    int col = j0 + wc + ni * 16 + lm;
    float bias = pb[col];
#pragma unroll
    for (int mi = 0; mi < 4; ++mi)
#pragma unroll
      for (int r = 0; r < 4; ++r) {
        int row = m0 + wr + mi * 16 + lg * 4 + r;
        xo[(size_t)row * DIM + col] = acc[mi][ni][r] + bias;
      }
  }
}

extern "C" void kernel_launch(void* const* d_in, const int* in_sizes, int n_in,
                              void* d_out, int out_size, void* d_ws, size_t ws_size,
                              hipStream_t stream) {
  (void)in_sizes; (void)n_in; (void)out_size; (void)ws_size;
  const float* x       = (const float*)d_in[0];
  const float* qconv_w = (const float*)d_in[1];
  const float* rw      = (const float*)d_in[2];
  const float* rb      = (const float*)d_in[3];
  const float* gamma   = (const float*)d_in[4];
  const float* beta    = (const float*)d_in[5];
  const float* mean    = (const float*)d_in[6];
  const float* var     = (const float*)d_in[7];
  const float* pw      = (const float*)d_in[8];
  const float* pb      = (const float*)d_in[9];

  float* xo   = (float*)d_out;
  float* attn = xo + (size_t)NB * NN * DIM;  // attn_next output region

  char* ws = (char*)d_ws;
  ushort* q    = (ushort*)(ws);                 // [8][1024][768] bf16: 12,582,912 B
  ushort* qT   = (ushort*)(ws + 12582912);      // [8][768][1024] bf16: 12,582,912 B
  ushort* wT   = (ushort*)(ws + 25165824);      // [768][768] bf16:      1,179,648 B
  ushort* outb = (ushort*)(ws + 26345472);      // [8192][768] bf16:    12,582,912 B
  float*  csum = (float*)(ws + 38928384);       // [8][768] f32:            24,576 B

  hipLaunchKernelGGL(k_prep_w, dim3(12, 12), dim3(256), 0, stream, pw, wT);
  hipLaunchKernelGGL(k_conv, dim3(NB * NN), dim3(256), 0, stream, x, qconv_w, q);
  hipLaunchKernelGGL(k_transpose_q, dim3(16, 12, NB), dim3(256), 0, stream, q, qT);
  hipLaunchKernelGGL(k_colsum, dim3(6, NB), dim3(128), 0, stream, q, csum);
  hipLaunchKernelGGL(k_attn_fused, dim3(512), dim3(512), 0, stream, q, qT, csum,
                     rw, rb, gamma, beta, mean, var, attn, outb);
  hipLaunchKernelGGL(k_proj, dim3(64, 6), dim3(256), 0, stream, outb, wT, pb, xo);
}

// Round 6
// 309.069 us; speedup vs baseline: 1.8428x; 1.2992x over previous
//
#include <hip/hip_runtime.h>

#define NB 8
#define NN 1024
#define NH 8
#define HD 96
#define DIM 768

typedef __bf16 bf16x8 __attribute__((ext_vector_type(8)));
typedef float f32x4 __attribute__((ext_vector_type(4)));
typedef unsigned short u16x8 __attribute__((ext_vector_type(8)));

__device__ __forceinline__ ushort f2bf(float f) {
  uint u = __float_as_uint(f);
  u += 0x7fffu + ((u >> 16) & 1u);
  return (ushort)(u >> 16);
}
__device__ __forceinline__ float bf2f(ushort u) {
  return __uint_as_float(((uint)u) << 16);
}

// ---------------- K0b: proj_w [768][768] f32 -> wT bf16 [j][d] ----------------
__global__ __launch_bounds__(256) void k_prep_w(const float* __restrict__ pw,
                                                ushort* __restrict__ wT) {
  __shared__ ushort tile[64][72];
  int d0 = blockIdx.x * 64;
  int j0 = blockIdx.y * 64;
  int t = threadIdx.x;
  {
    int r = t >> 2;
    int ch = (t & 3) * 16;
    const float* src = pw + (size_t)(d0 + r) * DIM + j0 + ch;
#pragma unroll
    for (int i = 0; i < 16; i += 4) {
      float4 v = *(const float4*)(src + i);
      tile[ch + i + 0][r] = f2bf(v.x);
      tile[ch + i + 1][r] = f2bf(v.y);
      tile[ch + i + 2][r] = f2bf(v.z);
      tile[ch + i + 3][r] = f2bf(v.w);
    }
  }
  __syncthreads();
  {
    int j = t >> 2;
    int ch = (t & 3) * 16;
    union { ushort u[16]; uint4 v[2]; } tmp;
#pragma unroll
    for (int i = 0; i < 16; ++i) tmp.u[i] = tile[j][ch + i];
    uint4* dst = (uint4*)(wT + (size_t)(j0 + j) * DIM + d0 + ch);
    dst[0] = tmp.v[0]; dst[1] = tmp.v[1];
  }
}

// ---------------- K1: 3x3 SAME conv per 16x16x3 token image -> q bf16 ----------------
__global__ __launch_bounds__(256) void k_conv(const float* __restrict__ x,
                                              const float* __restrict__ w,
                                              ushort* __restrict__ q) {
  __shared__ float xs[768];
  __shared__ float ws[81];
  __shared__ ushort os[768];
  int token = blockIdx.x;
  int t = threadIdx.x;
  const float4* xin = (const float4*)(x + (size_t)token * DIM);
  if (t < 192) ((float4*)xs)[t] = xin[t];
  if (t < 81) ws[t] = w[t];
  __syncthreads();
  int r = t >> 4, c = t & 15;
  float a0 = 0.f, a1 = 0.f, a2 = 0.f;
#pragma unroll
  for (int dr = 0; dr < 3; ++dr) {
    int rr = r + dr - 1;
    bool rok = (rr >= 0) & (rr < 16);
#pragma unroll
    for (int dc = 0; dc < 3; ++dc) {
      int cc = c + dc - 1;
      bool ok = rok & (cc >= 0) & (cc < 16);
#pragma unroll
      for (int ci = 0; ci < 3; ++ci) {
        int idx = ok ? (rr * 16 + cc) * 3 + ci : 0;
        float xv = xs[idx];
        xv = ok ? xv : 0.f;
        const float* wp = ws + ((dr * 3 + dc) * 3 + ci) * 3;
        a0 += xv * wp[0]; a1 += xv * wp[1]; a2 += xv * wp[2];
      }
    }
  }
  os[t * 3 + 0] = f2bf(a0);
  os[t * 3 + 1] = f2bf(a1);
  os[t * 3 + 2] = f2bf(a2);
  __syncthreads();
  uint4* dst = (uint4*)(q + (size_t)token * DIM);
  if (t < 96) dst[t] = ((const uint4*)os)[t];
}

// ---------------- K1b: q [b][n][d] -> qT [b][d][n] (bf16) ----------------
__global__ __launch_bounds__(256) void k_transpose_q(const ushort* __restrict__ q,
                                                     ushort* __restrict__ qT) {
  __shared__ ushort tile[64][72];
  int bb = blockIdx.z;
  int n0 = blockIdx.x * 64;
  int d0 = blockIdx.y * 64;
  int t = threadIdx.x;
  {
    int r = t >> 2;
    int cq = (t & 3) * 16;
    const ushort* src = q + ((size_t)(bb * NN) + n0 + r) * DIM + d0 + cq;
    uint4 v0 = *(const uint4*)src;
    uint4 v1 = *(const uint4*)(src + 8);
    *(uint4*)&tile[r][cq] = v0;
    *(uint4*)&tile[r][cq + 8] = v1;
  }
  __syncthreads();
  {
    int d = t >> 2;
    int nch = (t & 3) * 16;
    union { ushort u[16]; uint4 v[2]; } tmp;
#pragma unroll
    for (int j = 0; j < 16; ++j) tmp.u[j] = tile[nch + j][d];
    uint4* dst = (uint4*)(qT + ((size_t)(bb * DIM) + d0 + d) * NN + n0 + nch);
    dst[0] = tmp.v[0]; dst[1] = tmp.v[1];
  }
}

// ---------------- K1c: colsum[b][d] = sum_n q[b][n][d] ----------------
__global__ __launch_bounds__(128) void k_colsum(const ushort* __restrict__ q,
                                                float* __restrict__ cs) {
  int bb = blockIdx.y;
  int c = blockIdx.x * 128 + threadIdx.x;
  const ushort* p = q + (size_t)bb * NN * DIM + c;
  float s = 0.f;
#pragma unroll 16
  for (int n = 0; n < NN; ++n) s += bf2f(p[(size_t)n * DIM]);
  cs[bb * DIM + c] = s;
}

// ---------------- K2a: rowsum kernel -> inv[b][h][n] (barrier-free) ----------------
// 512 blocks x 256 thr = 2048 independent waves. Wave: (b, h, 32-row group).
// MFMA chain per element identical to k_attn_pv phase 1 (bitwise-consistent exp inputs).
__global__ __launch_bounds__(256) void k_rowsum(const ushort* __restrict__ q,
                                                float* __restrict__ invb) {
  const int lin = blockIdx.x;
  const int bb = lin & 7;
  const int idx = lin >> 3;
  const int hh = idx & 7;
  const int ng = idx >> 3;  // 0..7
  const int t = threadIdx.x;
  const int wv = t >> 6, lane = t & 63;
  const int lm = lane & 15, lg = lane >> 4;
  const int n0 = ng * 128 + wv * 32;
  const float scale = 0.10206207261596575f;  // 96^-0.5

  const ushort* qb = q + (size_t)bb * NN * DIM;
  const ushort* kb = qb + hh * HD + (size_t)lm * DIM + lg * 8;

  bf16x8 qf[2][3];
#pragma unroll
  for (int nf = 0; nf < 2; ++nf)
#pragma unroll
    for (int ks = 0; ks < 3; ++ks)
      qf[nf][ks] = *(const bf16x8*)(qb + (size_t)(n0 + nf * 16 + lm) * DIM
                                     + hh * HD + ks * 32 + lg * 8);

  float rs[2][4] = {};
  for (int mt = 0; mt < 16; ++mt) {
    const int m0 = mt * 64;
#pragma unroll
    for (int mf = 0; mf < 4; ++mf) {
      const ushort* kp = kb + (size_t)(m0 + mf * 16) * DIM;
      bf16x8 k0 = *(const bf16x8*)(kp);
      bf16x8 k1 = *(const bf16x8*)(kp + 32);
      bf16x8 k2 = *(const bf16x8*)(kp + 64);
      f32x4 s0 = {}, s1 = {};
      s0 = __builtin_amdgcn_mfma_f32_16x16x32_bf16(qf[0][0], k0, s0, 0, 0, 0);
      s0 = __builtin_amdgcn_mfma_f32_16x16x32_bf16(qf[0][1], k1, s0, 0, 0, 0);
      s0 = __builtin_amdgcn_mfma_f32_16x16x32_bf16(qf[0][2], k2, s0, 0, 0, 0);
      s1 = __builtin_amdgcn_mfma_f32_16x16x32_bf16(qf[1][0], k0, s1, 0, 0, 0);
      s1 = __builtin_amdgcn_mfma_f32_16x16x32_bf16(qf[1][1], k1, s1, 0, 0, 0);
      s1 = __builtin_amdgcn_mfma_f32_16x16x32_bf16(qf[1][2], k2, s1, 0, 0, 0);
#pragma unroll
      for (int r = 0; r < 4; ++r) {
        rs[0][r] += __expf(s0[r] * scale);
        rs[1][r] += __expf(s1[r] * scale);
      }
    }
  }
#pragma unroll
  for (int nf = 0; nf < 2; ++nf)
#pragma unroll
    for (int r = 0; r < 4; ++r) {
      float s = rs[nf][r];
      s += __shfl_xor(s, 1); s += __shfl_xor(s, 2);
      s += __shfl_xor(s, 4); s += __shfl_xor(s, 8);
      if (lm == 0)
        invb[(size_t)(bb * 8 + hh) * NN + n0 + nf * 16 + lg * 4 + r] = 1.f / s;
    }
}

// ---------------- K2b: fused QK^T(recompute) + normalize + mix/BN + attn + PV ----------
// 512 thr = 8 waves, wave w = head (QK) and channel g (mix/PV). QBLK=32 rows (nf=2).
// m-range split in half across 2 blocks -> grid 512 = 2 blocks/CU; PV partials via
// atomicAdd f32 (exactly 2 commutative contributions per cell -> deterministic).
// P double-buffered (2x32KB): ONE barrier per mt-iter.
__global__ __launch_bounds__(512, 2) void k_attn_pv(
    const ushort* __restrict__ q, const ushort* __restrict__ qT,
    const float* __restrict__ invb, const float* __restrict__ rw,
    const float* __restrict__ gamma, const float* __restrict__ beta,
    const float* __restrict__ mean, const float* __restrict__ var,
    const float* __restrict__ rb,
    float* __restrict__ attn, float* __restrict__ pacc) {
  __shared__ ushort P[2][16384];  // [2][8 h][32 n][64 m] bf16, XOR-swizzled

  const int lin = blockIdx.x;
  const int bb = lin & 7;          // XCD L2 locality: batch per XCD
  const int idx = lin >> 3;
  const int nt = idx >> 1;         // 0..31
  const int mh = idx & 1;          // m half
  const int n0 = nt * 32;
  const int mbase = mh * 512;
  const int t = threadIdx.x;
  const int w = t >> 6, lane = t & 63;
  const int lm = lane & 15, lg = lane >> 4;
  const float scale = 0.10206207261596575f;

  float wreg[8];
#pragma unroll
  for (int h = 0; h < 8; ++h) wreg[h] = rw[h * 8 + w];
  const float effs = gamma[w] * __frsqrt_rn(var[w] + 1e-3f);
  const float effb = (rb[w] - mean[w]) * effs + beta[w];

  const ushort* qb = q + (size_t)bb * NN * DIM;
  const ushort* vb = qT + (size_t)bb * DIM * NN;
  const ushort* kb = qb + w * HD + (size_t)lm * DIM + lg * 8;

  bf16x8 qf[2][3];
#pragma unroll
  for (int nf = 0; nf < 2; ++nf)
#pragma unroll
    for (int ks = 0; ks < 3; ++ks)
      qf[nf][ks] = *(const bf16x8*)(qb + (size_t)(n0 + nf * 16 + lm) * DIM
                                     + w * HD + ks * 32 + lg * 8);
  float inv[2][4];
#pragma unroll
  for (int nf = 0; nf < 2; ++nf)
#pragma unroll
    for (int r = 0; r < 4; ++r)
      inv[nf][r] = invb[(size_t)(bb * 8 + w) * NN + n0 + nf * 16 + lg * 4 + r];

  f32x4 oacc[2][6] = {};

  for (int mt = 0; mt < 8; ++mt) {
    const int m0 = mbase + mt * 64;
    char* Pc = (char*)P + (mt & 1) * 32768;
    // phase 1: recompute S (identical chains as k_rowsum), normalize, p -> LDS[cur]
#pragma unroll
    for (int mf = 0; mf < 4; ++mf) {
      const ushort* kp = kb + (size_t)(m0 + mf * 16) * DIM;
      bf16x8 k0 = *(const bf16x8*)(kp);
      bf16x8 k1 = *(const bf16x8*)(kp + 32);
      bf16x8 k2 = *(const bf16x8*)(kp + 64);
      f32x4 s0 = {}, s1 = {};
      s0 = __builtin_amdgcn_mfma_f32_16x16x32_bf16(qf[0][0], k0, s0, 0, 0, 0);
      s0 = __builtin_amdgcn_mfma_f32_16x16x32_bf16(qf[0][1], k1, s0, 0, 0, 0);
      s0 = __builtin_amdgcn_mfma_f32_16x16x32_bf16(qf[0][2], k2, s0, 0, 0, 0);
      s1 = __builtin_amdgcn_mfma_f32_16x16x32_bf16(qf[1][0], k0, s1, 0, 0, 0);
      s1 = __builtin_amdgcn_mfma_f32_16x16x32_bf16(qf[1][1], k1, s1, 0, 0, 0);
      s1 = __builtin_amdgcn_mfma_f32_16x16x32_bf16(qf[1][2], k2, s1, 0, 0, 0);
      const int mb = 2 * (mf * 16 + lm);
#pragma unroll
      for (int r = 0; r < 4; ++r) {
        int n = lg * 4 + r;
        int sw = (n & 7) << 4;
        float e0 = __expf(s0[r] * scale) * inv[0][r];
        *(ushort*)(Pc + w * 4096 + n * 128 + (mb ^ sw)) = f2bf(e0);
        float e1 = __expf(s1[r] * scale) * inv[1][r];
        *(ushort*)(Pc + w * 4096 + (n + 16) * 128 + (mb ^ sw)) = f2bf(e1);
      }
    }
    __syncthreads();
    // phase 2: mix heads -> g=w, BN-affine store to attn, pack PV A-frags
    bf16x8 pmf[2][2];
#pragma unroll
    for (int nf = 0; nf < 2; ++nf) {
      int n = nf * 16 + lm;
      int swz = (n & 7) << 4;
#pragma unroll
      for (int ks = 0; ks < 2; ++ks) {
        int rbase = n * 128 + ((2 * (ks * 32 + lg * 8)) ^ swz);
        float mix[8];
#pragma unroll
        for (int j = 0; j < 8; ++j) mix[j] = 0.f;
#pragma unroll
        for (int h = 0; h < 8; ++h) {
          u16x8 pu = *(const u16x8*)(Pc + h * 4096 + rbase);
#pragma unroll
          for (int j = 0; j < 8; ++j) mix[j] += bf2f(pu[j]) * wreg[h];
        }
        f32x4 o0, o1;
        o0[0] = mix[0] * effs + effb; o0[1] = mix[1] * effs + effb;
        o0[2] = mix[2] * effs + effb; o0[3] = mix[3] * effs + effb;
        o1[0] = mix[4] * effs + effb; o1[1] = mix[5] * effs + effb;
        o1[2] = mix[6] * effs + effb; o1[3] = mix[7] * effs + effb;
        size_t arow = ((size_t)(bb * 8 + w) * NN + (n0 + n)) * NN + m0 + ks * 32 + lg * 8;
        __builtin_nontemporal_store(o0, (f32x4*)(attn + arow));
        __builtin_nontemporal_store(o1, (f32x4*)(attn + arow + 4));
        u16x8 pk;
#pragma unroll
        for (int j = 0; j < 8; ++j) pk[j] = f2bf(mix[j]);
        pmf[nf][ks] = *(bf16x8*)&pk;
      }
    }
    // phase 3: PV MFMA (next iter writes the other P buffer; barrier at its top)
#pragma unroll
    for (int ks = 0; ks < 2; ++ks) {
      bf16x8 vf[6];
#pragma unroll
      for (int df = 0; df < 6; ++df)
        vf[df] = *(const bf16x8*)(vb + (size_t)(w * HD + df * 16 + lm) * NN
                                   + m0 + ks * 32 + lg * 8);
#pragma unroll
      for (int df = 0; df < 6; ++df) {
        oacc[0][df] = __builtin_amdgcn_mfma_f32_16x16x32_bf16(pmf[0][ks], vf[df], oacc[0][df], 0, 0, 0);
        oacc[1][df] = __builtin_amdgcn_mfma_f32_16x16x32_bf16(pmf[1][ks], vf[df], oacc[1][df], 0, 0, 0);
      }
    }
  }

  // epilogue: accumulate raw PV partial into pacc (f32, 2 contributions per cell)
#pragma unroll
  for (int df = 0; df < 6; ++df) {
    int col = w * HD + df * 16 + lm;
#pragma unroll
    for (int nf = 0; nf < 2; ++nf)
#pragma unroll
      for (int r = 0; r < 4; ++r) {
        int row = n0 + nf * 16 + lg * 4 + r;
        unsafeAtomicAdd(&pacc[(size_t)(bb * NN + row) * DIM + col], oacc[nf][df][r]);
      }
  }
}

// ---------------- K2c: outb = bf16(effs*pacc + effb*colsum) ----------------
__global__ __launch_bounds__(256) void k_sumfix(const float* __restrict__ pacc,
    const float* __restrict__ cs,
    const float* __restrict__ gamma, const float* __restrict__ beta,
    const float* __restrict__ mean, const float* __restrict__ var,
    const float* __restrict__ rb, ushort* __restrict__ outb) {
  size_t base = ((size_t)blockIdx.x * 256 + threadIdx.x) * 4;
  int col = (int)(base % DIM);
  int brow = (int)(base / DIM);
  int bb = brow >> 10;
  int g = col / 96;
  float effs = gamma[g] * __frsqrt_rn(var[g] + 1e-3f);
  float effb = (rb[g] - mean[g]) * effs + beta[g];
  f32x4 p = *(const f32x4*)(pacc + base);
  f32x4 c = *(const f32x4*)(cs + bb * DIM + col);
  ushort4 o;
  o.x = f2bf(p[0] * effs + effb * c[0]);
  o.y = f2bf(p[1] * effs + effb * c[1]);
  o.z = f2bf(p[2] * effs + effb * c[2]);
  o.w = f2bf(p[3] * effs + effb * c[3]);
  *(ushort4*)(outb + base) = o;
}

// ---------------- K6: xo = out @ proj_w + proj_b (bf16 MFMA, fp32 out) ----------------
__global__ __launch_bounds__(256) void k_proj(const ushort* __restrict__ outb,
                                              const ushort* __restrict__ wT,
                                              const float* __restrict__ pb,
                                              float* __restrict__ xo) {
  __shared__ ushort As[128][72];
  __shared__ ushort Bs[128][72];
  int m0 = blockIdx.x * 128;
  int j0 = blockIdx.y * 128;
  int t = threadIdx.x;
  int wv = t >> 6, lane = t & 63;
  int wr = (wv >> 1) * 64, wc = (wv & 1) * 64;
  int lm = lane & 15, lg = lane >> 4;
  f32x4 acc[4][4] = {};
  for (int kk = 0; kk < 12; ++kk) {
    int k0 = kk * 64;
    __syncthreads();
    for (int i = t; i < 1024; i += 256) {
      int row = i >> 3;
      int c = (i & 7) * 8;
      *(uint4*)&As[row][c] = *(const uint4*)(outb + (size_t)(m0 + row) * DIM + k0 + c);
      *(uint4*)&Bs[row][c] = *(const uint4*)(wT + (size_t)(j0 + row) * DIM + k0 + c);
    }
    __syncthreads();
#pragma unroll
    for (int ks = 0; ks < 2; ++ks) {
      bf16x8 af[4], bfr[4];
#pragma unroll
      for (int mi = 0; mi < 4; ++mi)
        af[mi] = *(const bf16x8*)&As[wr + mi * 16 + lm][ks * 32 + lg * 8];
#pragma unroll
      for (int ni = 0; ni < 4; ++ni)
        bfr[ni] = *(const bf16x8*)&Bs[wc + ni * 16 + lm][ks * 32 + lg * 8];
#pragma unroll
      for (int mi = 0; mi < 4; ++mi)
#pragma unroll
        for (int ni = 0; ni < 4; ++ni)
          acc[mi][ni] = __builtin_amdgcn_mfma_f32_16x16x32_bf16(af[mi], bfr[ni], acc[mi][ni], 0, 0, 0);
    }
  }
#pragma unroll
  for (int ni = 0; ni < 4; ++ni) {
    int col = j0 + wc + ni * 16 + lm;
    float bias = pb[col];
#pragma unroll
    for (int mi = 0; mi < 4; ++mi)
#pragma unroll
      for (int r = 0; r < 4; ++r) {
        int row = m0 + wr + mi * 16 + lg * 4 + r;
        xo[(size_t)row * DIM + col] = acc[mi][ni][r] + bias;
      }
  }
}

extern "C" void kernel_launch(void* const* d_in, const int* in_sizes, int n_in,
                              void* d_out, int out_size, void* d_ws, size_t ws_size,
                              hipStream_t stream) {
  (void)in_sizes; (void)n_in; (void)out_size; (void)ws_size;
  const float* x       = (const float*)d_in[0];
  const float* qconv_w = (const float*)d_in[1];
  const float* rw      = (const float*)d_in[2];
  const float* rb      = (const float*)d_in[3];
  const float* gamma   = (const float*)d_in[4];
  const float* beta    = (const float*)d_in[5];
  const float* mean    = (const float*)d_in[6];
  const float* var     = (const float*)d_in[7];
  const float* pw      = (const float*)d_in[8];
  const float* pb      = (const float*)d_in[9];

  float* xo   = (float*)d_out;
  float* attn = xo + (size_t)NB * NN * DIM;  // attn_next output region

  char* ws = (char*)d_ws;
  ushort* q    = (ushort*)(ws);                 // [8][1024][768] bf16: 12,582,912 B
  ushort* qT   = (ushort*)(ws + 12582912);      // [8][768][1024] bf16: 12,582,912 B
  ushort* wT   = (ushort*)(ws + 25165824);      // [768][768] bf16:      1,179,648 B
  ushort* outb = (ushort*)(ws + 26345472);      // [8192][768] bf16:    12,582,912 B
  float*  csum = (float*)(ws + 38928384);       // [8][768] f32:            24,576 B
  float*  invb = (float*)(ws + 38952960);       // [8][8][1024] f32:       262,144 B
  float*  pacc = (float*)(ws + 39215104);       // [8192][768] f32:     25,165,824 B
                                                // total: 64,380,928 B

  hipMemsetAsync(pacc, 0, (size_t)NB * NN * DIM * sizeof(float), stream);
  hipLaunchKernelGGL(k_prep_w, dim3(12, 12), dim3(256), 0, stream, pw, wT);
  hipLaunchKernelGGL(k_conv, dim3(NB * NN), dim3(256), 0, stream, x, qconv_w, q);
  hipLaunchKernelGGL(k_transpose_q, dim3(16, 12, NB), dim3(256), 0, stream, q, qT);
  hipLaunchKernelGGL(k_colsum, dim3(6, NB), dim3(128), 0, stream, q, csum);
  hipLaunchKernelGGL(k_rowsum, dim3(512), dim3(256), 0, stream, q, invb);
  hipLaunchKernelGGL(k_attn_pv, dim3(512), dim3(512), 0, stream, q, qT, invb,
                     rw, gamma, beta, mean, var, rb, attn, pacc);
  hipLaunchKernelGGL(k_sumfix, dim3(6144), dim3(256), 0, stream, pacc, csum,
                     gamma, beta, mean, var, rb, outb);
  hipLaunchKernelGGL(k_proj, dim3(64, 6), dim3(256), 0, stream, outb, wT, pb, xo);
}